// Round 15
// baseline (311.558 us; speedup 1.0000x reference)
//
#include <hip/hip_runtime.h>
#include <math.h>

#define BB 8
#define TT 512
#define DD 256
#define DIM 512
#define KW 4
#define MM 2
#define HH 4
#define HDIM 64
#define LL 2
#define VV 272

typedef __attribute__((ext_vector_type(8))) short bf16x8;
typedef __attribute__((ext_vector_type(4))) float f32x4;

__device__ __forceinline__ float sigf(float x){ return 1.f/(1.f+__expf(-x)); }
__device__ __forceinline__ float siluf(float x){ return x/(1.f+__expf(-x)); }

__device__ __forceinline__ unsigned short f2bf(float f){
  unsigned int u = __float_as_uint(f);
  unsigned int r = (u + 0x7FFFu + ((u >> 16) & 1u)) >> 16;
  return (unsigned short)r;
}
__device__ __forceinline__ float bf2f(unsigned short s){
  return __uint_as_float(((unsigned int)s) << 16);
}

// DPP reduces (no DS ops)
__device__ __forceinline__ float xor1_add(float x){
  int y = __builtin_amdgcn_update_dpp(0, __float_as_int(x), 0xB1, 0xF, 0xF, true);
  return x + __int_as_float(y);
}
__device__ __forceinline__ float xor2_add(float x){
  int y = __builtin_amdgcn_update_dpp(0, __float_as_int(x), 0x4E, 0xF, 0xF, true);
  return x + __int_as_float(y);
}
__device__ __forceinline__ float ror4_add(float x){
  int y = __builtin_amdgcn_update_dpp(0, __float_as_int(x), 0x124, 0xF, 0xF, true);
  return x + __int_as_float(y);
}
__device__ __forceinline__ float ror8_add(float x){
  int y = __builtin_amdgcn_update_dpp(0, __float_as_int(x), 0x128, 0xF, 0xF, true);
  return x + __int_as_float(y);
}

// async global->LDS, 16B per lane. LDS dest is wave-uniform base + lane*16.
__device__ __forceinline__ void gl_lds16(const void* g, void* l){
  __builtin_amdgcn_global_load_lds(
      (const __attribute__((address_space(1))) unsigned int*)g,
      (__attribute__((address_space(3))) unsigned int*)l,
      16, 0, 0);
}

// ---------------- weight convert + transpose to bf16 [N][K] ----------------
#define LWB 589824
__global__ void k_cvt(const float* __restrict__ Wup, const float* __restrict__ Wgate,
                      const float* __restrict__ Wdown, const float* __restrict__ Wv,
                      const float* __restrict__ Wout, const float* __restrict__ emb,
                      unsigned short* __restrict__ wbf){
  int idx = blockIdx.x*256 + threadIdx.x;
  if (idx >= 2*LWB + VV*DD) return;
  float v;
  if (idx < 2*LWB){
    int l = (idx >= LWB) ? 1 : 0;
    int local = idx - l*LWB;
    if (local < 131072){ int n = local>>8, k = local&255;
      v = Wup[(size_t)l*131072 + k*DIM + n]; }
    else if (local < 262144){ local -= 131072; int n = local>>8, k = local&255;
      v = Wgate[(size_t)l*131072 + k*DIM + n]; }
    else if (local < 393216){ local -= 262144; int n = local>>9, k = local&511;
      v = Wdown[(size_t)l*131072 + k*DD + n]; }
    else if (local < 524288){ local -= 393216; int n = local>>8, k = local&255;
      v = Wv[(size_t)l*131072 + k*DIM + n]; }
    else { local -= 524288; int n = local>>8, k = local&255;
      v = Wout[(size_t)l*65536 + k*DD + n]; }
  } else {
    v = emb[idx - 2*LWB];
  }
  wbf[idx] = f2bf(v);
}

// ---------------- embedding gather ----------------
__global__ void k_embed(const int* __restrict__ ids, const float* __restrict__ emb,
                        float* __restrict__ x){
  int row = blockIdx.x;
  int d = threadIdx.x;
  x[row*DD + d] = emb[ids[row]*DD + d];
}

// ---------------- rmsnorm (row of 256) -> bf16 out, 1 wave/row ----------------
__global__ void k_rmsnorm(const float* __restrict__ in, const float* __restrict__ w,
                          unsigned short* __restrict__ out){
  int row = blockIdx.x;
  int l = threadIdx.x;             // 64
  float4 v = *(const float4*)&in[row*DD + l*4];
  float ss = v.x*v.x + v.y*v.y + v.z*v.z + v.w*v.w;
  #pragma unroll
  for (int o = 32; o > 0; o >>= 1) ss += __shfl_xor(ss, o, 64);
  float sc = rsqrtf(ss*(1.f/DD) + 1e-6f);
  float4 wv = *(const float4*)&w[l*4];
  ushort4 r;
  r.x = f2bf(v.x*sc*wv.x); r.y = f2bf(v.y*sc*wv.y);
  r.z = f2bf(v.z*sc*wv.z); r.w = f2bf(v.w*sc*wv.w);
  *(ushort4*)&out[row*DD + l*4] = r;
}

// -------- bf16 GEMM 64x64 tile (4 waves): C[4096,N] = A@Bt^T ----------------
// MODE 0: f32 C. MODE 1: bf16 C. MODE 2: both.
template<int MODE>
__global__ void __launch_bounds__(256) k_gemm64(const unsigned short* __restrict__ A,
                                                const unsigned short* __restrict__ Bt,
                                                float* __restrict__ Cf,
                                                unsigned short* __restrict__ Cb,
                                                int N, int K){
  __shared__ unsigned short as[64][72];
  __shared__ unsigned short bs[64][72];
  const int tid = threadIdx.x;
  const int w = tid >> 6, l = tid & 63;
  const int m0 = blockIdx.y*64, n0 = blockIdx.x*64;
  const int ar = tid >> 2, ac = (tid & 3)*16;
  f32x4 acc[4] = {};
  for (int k0 = 0; k0 < K; k0 += 64){
    { const bf16x8* src = (const bf16x8*)&A[(size_t)(m0+ar)*K + k0 + ac];
      *(bf16x8*)&as[ar][ac]   = src[0];
      *(bf16x8*)&as[ar][ac+8] = src[1];
    }
    { int n = n0 + ar;
      bf16x8 z; z = (bf16x8)(short)0;
      bf16x8 b0 = z, b1 = z;
      if (n < N){
        const bf16x8* src = (const bf16x8*)&Bt[(size_t)n*K + k0 + ac];
        b0 = src[0]; b1 = src[1];
      }
      *(bf16x8*)&bs[ar][ac]   = b0;
      *(bf16x8*)&bs[ar][ac+8] = b1;
    }
    __syncthreads();
    const int mr = w*16 + (l & 15);
    const int kb = (l >> 4)*8;
    #pragma unroll
    for (int kc2 = 0; kc2 < 2; ++kc2){
      bf16x8 af = *(const bf16x8*)&as[mr][kc2*32 + kb];
      #pragma unroll
      for (int nt = 0; nt < 4; ++nt){
        bf16x8 bfr = *(const bf16x8*)&bs[nt*16 + (l & 15)][kc2*32 + kb];
        acc[nt] = __builtin_amdgcn_mfma_f32_16x16x32_bf16(af, bfr, acc[nt], 0, 0, 0);
      }
    }
    __syncthreads();
  }
  #pragma unroll
  for (int nt = 0; nt < 4; ++nt){
    int col = n0 + nt*16 + (l & 15);
    if (col < N){
      #pragma unroll
      for (int r = 0; r < 4; ++r){
        int row = m0 + w*16 + (l >> 4)*4 + r;
        if (MODE == 0 || MODE == 2) Cf[(size_t)row*N + col] = acc[nt][r];
        if (MODE == 1 || MODE == 2) Cb[(size_t)row*N + col] = f2bf(acc[nt][r]);
      }
    }
  }
}

// -------- bf16 GEMM 128x64 tile (4 waves) — for full-grid cases ------------
template<int MODE>
__global__ void __launch_bounds__(256) k_gemm128(const unsigned short* __restrict__ A,
                                                 const unsigned short* __restrict__ Bt,
                                                 float* __restrict__ Cf,
                                                 unsigned short* __restrict__ Cb,
                                                 int N, int K){
  __shared__ unsigned short as[128][72];
  __shared__ unsigned short bs[64][72];
  const int tid = threadIdx.x;
  const int w = tid >> 6, l = tid & 63;
  const int m0 = blockIdx.y*128, n0 = blockIdx.x*64;
  const int ar = tid >> 1, ac = (tid & 1)*32;
  const int br = tid >> 2, bc = (tid & 3)*16;
  f32x4 acc[2][4] = {};
  for (int k0 = 0; k0 < K; k0 += 64){
    { const bf16x8* src = (const bf16x8*)&A[(size_t)(m0+ar)*K + k0 + ac];
      *(bf16x8*)&as[ar][ac]    = src[0];
      *(bf16x8*)&as[ar][ac+8]  = src[1];
      *(bf16x8*)&as[ar][ac+16] = src[2];
      *(bf16x8*)&as[ar][ac+24] = src[3];
    }
    { int n = n0 + br;
      bf16x8 z; z = (bf16x8)(short)0;
      bf16x8 b0 = z, b1 = z;
      if (n < N){
        const bf16x8* s = (const bf16x8*)&Bt[(size_t)n*K + k0 + bc];
        b0 = s[0]; b1 = s[1];
      }
      *(bf16x8*)&bs[br][bc]   = b0;
      *(bf16x8*)&bs[br][bc+8] = b1;
    }
    __syncthreads();
    const int lr = l & 15, kb = (l >> 4)*8;
    #pragma unroll
    for (int kc2 = 0; kc2 < 2; ++kc2){
      bf16x8 af0 = *(const bf16x8*)&as[w*32 + lr][kc2*32 + kb];
      bf16x8 af1 = *(const bf16x8*)&as[w*32 + 16 + lr][kc2*32 + kb];
      #pragma unroll
      for (int nt = 0; nt < 4; ++nt){
        bf16x8 bfr = *(const bf16x8*)&bs[nt*16 + lr][kc2*32 + kb];
        acc[0][nt] = __builtin_amdgcn_mfma_f32_16x16x32_bf16(af0, bfr, acc[0][nt], 0, 0, 0);
        acc[1][nt] = __builtin_amdgcn_mfma_f32_16x16x32_bf16(af1, bfr, acc[1][nt], 0, 0, 0);
      }
    }
    __syncthreads();
  }
  const int lr = l & 15;
  #pragma unroll
  for (int mt = 0; mt < 2; ++mt){
    #pragma unroll
    for (int nt = 0; nt < 4; ++nt){
      int col = n0 + nt*16 + lr;
      if (col < N){
        #pragma unroll
        for (int r = 0; r < 4; ++r){
          int row = m0 + w*32 + mt*16 + (l >> 4)*4 + r;
          if (MODE == 0 || MODE == 2) Cf[(size_t)row*N + col] = acc[mt][nt][r];
          if (MODE == 1 || MODE == 2) Cb[(size_t)row*N + col] = f2bf(acc[mt][nt][r]);
        }
      }
    }
  }
}

// ---- dual GEMM: Cu = A@BuT^T, Cg = A@BgT^T (shared A), BM=128 BN=64 -------
__global__ void __launch_bounds__(256) k_gemm_up(const unsigned short* __restrict__ A,
                                                 const unsigned short* __restrict__ But,
                                                 const unsigned short* __restrict__ Bgt,
                                                 unsigned short* __restrict__ Cu,
                                                 unsigned short* __restrict__ Cg){
  __shared__ unsigned short as[128][72];
  __shared__ unsigned short bu[64][72];
  __shared__ unsigned short bg[64][72];
  const int tid = threadIdx.x;
  const int w = tid >> 6, l = tid & 63;
  const int m0 = blockIdx.y*128, n0 = blockIdx.x*64;
  const int ar = tid >> 1, ac = (tid & 1)*32;
  const int br = tid >> 2, bc = (tid & 3)*16;
  f32x4 accu[2][4] = {}; f32x4 accg[2][4] = {};
  for (int k0 = 0; k0 < DD; k0 += 64){
    { const bf16x8* src = (const bf16x8*)&A[(size_t)(m0+ar)*DD + k0 + ac];
      *(bf16x8*)&as[ar][ac]    = src[0];
      *(bf16x8*)&as[ar][ac+8]  = src[1];
      *(bf16x8*)&as[ar][ac+16] = src[2];
      *(bf16x8*)&as[ar][ac+24] = src[3];
    }
    { const bf16x8* s0 = (const bf16x8*)&But[(size_t)(n0+br)*DD + k0 + bc];
      *(bf16x8*)&bu[br][bc]   = s0[0];
      *(bf16x8*)&bu[br][bc+8] = s0[1];
      const bf16x8* s1 = (const bf16x8*)&Bgt[(size_t)(n0+br)*DD + k0 + bc];
      *(bf16x8*)&bg[br][bc]   = s1[0];
      *(bf16x8*)&bg[br][bc+8] = s1[1];
    }
    __syncthreads();
    const int lr = l & 15, kb = (l >> 4)*8;
    #pragma unroll
    for (int kc2 = 0; kc2 < 2; ++kc2){
      bf16x8 af0 = *(const bf16x8*)&as[w*32 + lr][kc2*32 + kb];
      bf16x8 af1 = *(const bf16x8*)&as[w*32 + 16 + lr][kc2*32 + kb];
      #pragma unroll
      for (int nt = 0; nt < 4; ++nt){
        bf16x8 b0 = *(const bf16x8*)&bu[nt*16 + lr][kc2*32 + kb];
        accu[0][nt] = __builtin_amdgcn_mfma_f32_16x16x32_bf16(af0, b0, accu[0][nt], 0, 0, 0);
        accu[1][nt] = __builtin_amdgcn_mfma_f32_16x16x32_bf16(af1, b0, accu[1][nt], 0, 0, 0);
        bf16x8 b1 = *(const bf16x8*)&bg[nt*16 + lr][kc2*32 + kb];
        accg[0][nt] = __builtin_amdgcn_mfma_f32_16x16x32_bf16(af0, b1, accg[0][nt], 0, 0, 0);
        accg[1][nt] = __builtin_amdgcn_mfma_f32_16x16x32_bf16(af1, b1, accg[1][nt], 0, 0, 0);
      }
    }
    __syncthreads();
  }
  const int lr = l & 15;
  #pragma unroll
  for (int mt = 0; mt < 2; ++mt){
    #pragma unroll
    for (int nt = 0; nt < 4; ++nt){
      int col = n0 + nt*16 + lr;
      #pragma unroll
      for (int r = 0; r < 4; ++r){
        int row = m0 + w*32 + mt*16 + (l >> 4)*4 + r;
        Cu[(size_t)row*DIM + col] = f2bf(accu[mt][nt][r]);
        Cg[(size_t)row*DIM + col] = f2bf(accg[mt][nt][r]);
      }
    }
  }
}

// ---- Wout GEMM 64x64: fused comb (A = p0+p1) + resid (x += y + A@WoutT^T) --
__global__ void __launch_bounds__(256) k_gemm_wout(const float* __restrict__ p0,
                                                   const float* __restrict__ p1,
                                                   const unsigned short* __restrict__ Bt,
                                                   const float* __restrict__ y,
                                                   float* __restrict__ x){
  __shared__ unsigned short as[64][72];
  __shared__ unsigned short bs[64][72];
  const int tid = threadIdx.x;
  const int w = tid >> 6, l = tid & 63;
  const int m0 = blockIdx.y*64, n0 = blockIdx.x*64;
  const int ar = tid >> 2, ac = (tid & 3)*16;
  f32x4 acc[4] = {};
  for (int k0 = 0; k0 < DD; k0 += 64){
    #pragma unroll
    for (int j = 0; j < 4; ++j){
      size_t off = (size_t)(m0+ar)*DD + k0 + ac + j*4;
      float4 a = *(const float4*)&p0[off];
      float4 b = *(const float4*)&p1[off];
      a.x += b.x; a.y += b.y; a.z += b.z; a.w += b.w;
      ushort4 u = make_ushort4(f2bf(a.x), f2bf(a.y), f2bf(a.z), f2bf(a.w));
      *(ushort4*)&as[ar][ac + j*4] = u;
    }
    { const bf16x8* src = (const bf16x8*)&Bt[(size_t)(n0+ar)*DD + k0 + ac];
      *(bf16x8*)&bs[ar][ac]   = src[0];
      *(bf16x8*)&bs[ar][ac+8] = src[1];
    }
    __syncthreads();
    const int mr = w*16 + (l & 15);
    const int kb = (l >> 4)*8;
    #pragma unroll
    for (int kc2 = 0; kc2 < 2; ++kc2){
      bf16x8 af = *(const bf16x8*)&as[mr][kc2*32 + kb];
      #pragma unroll
      for (int nt = 0; nt < 4; ++nt){
        bf16x8 bfr = *(const bf16x8*)&bs[nt*16 + (l & 15)][kc2*32 + kb];
        acc[nt] = __builtin_amdgcn_mfma_f32_16x16x32_bf16(af, bfr, acc[nt], 0, 0, 0);
      }
    }
    __syncthreads();
  }
  #pragma unroll
  for (int nt = 0; nt < 4; ++nt){
    int col = n0 + nt*16 + (l & 15);
    #pragma unroll
    for (int r = 0; r < 4; ++r){
      int row = m0 + w*16 + (l >> 4)*4 + r;
      size_t off = (size_t)row*DD + col;
      x[off] = x[off] + y[off] + acc[nt][r];
    }
  }
}

// ------------ causal depthwise conv + silu gating, bf16 in/out ------------
__global__ void k_conv(const unsigned short* __restrict__ u,
                       const unsigned short* __restrict__ g,
                       const float* __restrict__ cw, const float* __restrict__ cb,
                       unsigned short* __restrict__ hh){
  int i8 = blockIdx.x*256 + threadIdx.x;    // over ROWS*DIM/8
  int cg = i8 & 63;
  int bt = i8 >> 6;
  int t  = bt & (TT-1);
  int c0 = cg*8;
  float acc[8];
  { float4 b0 = *(const float4*)&cb[c0];
    float4 b1 = *(const float4*)&cb[c0+4];
    acc[0]=b0.x; acc[1]=b0.y; acc[2]=b0.z; acc[3]=b0.w;
    acc[4]=b1.x; acc[5]=b1.y; acc[6]=b1.z; acc[7]=b1.w; }
  float wts[8][4];
  #pragma unroll
  for (int i = 0; i < 8; ++i) *(float4*)&wts[i][0] = *(const float4*)&cw[(c0+i)*KW];
  #pragma unroll
  for (int j = 0; j < KW; ++j){
    int dt_ = j - (KW-1);
    if (t + dt_ >= 0){
      bf16x8 uv = *(const bf16x8*)&u[(size_t)(bt + dt_)*DIM + c0];
      #pragma unroll
      for (int i = 0; i < 8; ++i)
        acc[i] = fmaf(bf2f((unsigned short)uv[i]), wts[i][j], acc[i]);
    }
  }
  bf16x8 gv = *(const bf16x8*)&g[(size_t)bt*DIM + c0];
  bf16x8 o;
  #pragma unroll
  for (int i = 0; i < 8; ++i){
    float h = siluf(acc[i]);
    o[i] = (short)f2bf(siluf(bf2f((unsigned short)gv[i])) * h);
  }
  *(bf16x8*)&hh[(size_t)bt*DIM + c0] = o;
}

// ---- fused: proj(small GEMM w/ packed weights) + scal + rk-normalize ----
// rk output is bf16 now (scan stages it as bf16 to fit 8 blocks/CU).
__global__ void __launch_bounds__(256) k_fused(const float* __restrict__ y,
    const float* __restrict__ Wg, const float* __restrict__ Wb,
    const float* __restrict__ Wa, const float* __restrict__ Wbl,
    const float* __restrict__ A_log, const float* __restrict__ dtb,
    unsigned short* __restrict__ rkb, float* __restrict__ scal){
  __shared__ float s_y[4][260];
  __shared__ float s_p[4][32];
  const int wv = threadIdx.x >> 6, l = threadIdx.x & 63;
  const int row = blockIdx.x*4 + wv;

  float4 yv = *(const float4*)&y[(size_t)row*DD + l*4];
  *(float4*)&s_y[wv][l*4] = yv;

  float ss = yv.x*yv.x + yv.y*yv.y + yv.z*yv.z + yv.w*yv.w;
  ss = xor1_add(ss); ss = xor2_add(ss);
  ss = ror4_add(ss); ss = ror8_add(ss);
  float inv = 1.f / fmaxf(sqrtf(ss), 1e-12f);
  ushort4 rv;
  rv.x = f2bf(yv.x*inv); rv.y = f2bf(yv.y*inv);
  rv.z = f2bf(yv.z*inv); rv.w = f2bf(yv.w*inv);
  *(ushort4*)&rkb[(size_t)row*DD + l*4] = rv;

  __syncthreads();

  const int j = (l < 28) ? l : 27;
  const float* wp; int stride;
  if (j < 4){ wp = Wg + j; stride = HH; }
  else if (j < 12){ int m=(j-4)>>2, h=(j-4)&3; wp = Wb + (size_t)m*DD*HH + h; stride = HH; }
  else if (j < 20){ int m=(j-12)>>2, h=(j-12)&3; wp = Wa + (size_t)m*DD*HH + h; stride = HH; }
  else { wp = Wbl + (j-20); stride = HH*MM; }
  float a0=0.f,a1=0.f,a2=0.f,a3=0.f;
  #pragma unroll 4
  for (int k = 0; k < DD; k += 4){
    a0 = fmaf(s_y[wv][k+0], wp[(k+0)*stride], a0);
    a1 = fmaf(s_y[wv][k+1], wp[(k+1)*stride], a1);
    a2 = fmaf(s_y[wv][k+2], wp[(k+2)*stride], a2);
    a3 = fmaf(s_y[wv][k+3], wp[(k+3)*stride], a3);
  }
  if (l < 28) s_p[wv][l] = (a0+a1)+(a2+a3);

  __syncthreads();

  if (l < 8){
    int m = l >> 2, h = l & 3;
    float gs  = sigf(s_p[wv][h]);
    float btv = sigf(s_p[wv][4 + m*4 + h]);
    float sp  = s_p[wv][12 + m*4 + h] + dtb[m*HH + h];
    sp = (sp > 15.f) ? sp : log1pf(__expf(sp));
    float dc  = __expf(-__expf(A_log[m*HH + h]) * sp);
    float l0 = s_p[wv][20 + h*2], l1 = s_p[wv][20 + h*2 + 1];
    float mx = fmaxf(l0, l1);
    float e0 = __expf(l0-mx), e1 = __expf(l1-mx);
    float bl = (m ? e1 : e0) / (e0 + e1);
    float4 o; o.x = dc; o.y = btv; o.z = bl*gs; o.w = 0.f;
    *(float4*)&scal[((size_t)row*MM + m)*(HH*4) + h*4] = o;
  }
}

// ---------------- sequential delta-memory scan, k-split-32 ----------
// grid = B*H*M*32 blocks (kq2 = 2 k's per wave), 64 threads = 1 wave.
// Lane: seg = l&31 (d-pair: d = seg*2, seg*2+1; S[2]/lane); klocal = l>>5.
// d-reduce within each 32-lane half: xor1+xor2+ror4+ror8 DPP + shfl_xor(16).
// pred(t+1) = read(t) carried in rrc. rk staged bf16 -> 20KB LDS, 8 blocks/CU
// = 2 waves/SIMD so two scan units interleave in each SIMD's stall bubbles.
// m=1 rotate_half acts exactly on each lane's (2s,2s+1) pair.

#define SSTEP(T_, WK, RK, PF, VB, SB) { \
  const float dc = SB.x, btv = SB.y, blg = SB.z; \
  const float v = VB; \
  { const int tn_ = ((T_)+2 < 64) ? (T_)+2 : 63; \
    ushort2 rw = *(const ushort2*)&s_rk[p][tn_][dbase]; \
    PF.x = bf2f(rw.x); PF.y = bf2f(rw.y); \
    VB = bf2f(s_v[p][tn_][vidx]); \
    SB = *(const float4*)&s_sc[p][tn_][0]; } \
  const float err = (v - dc*rrc)*btv; \
  float w0, w1, c0, c1; \
  if (ROT == 0){ w0 = WK.x; w1 = WK.y; c0 = RK.x; c1 = RK.y; } \
  else { w0 = -WK.y; w1 = WK.x; c0 = -RK.y; c1 = RK.x; } \
  S0 = fmaf(S0, dc, w0*err); \
  S1 = fmaf(S1, dc, w1*err); \
  float rr = S0*c0; rr = fmaf(S1, c1, rr); \
  rr = xor1_add(rr); rr = xor2_add(rr); rr = ror4_add(rr); rr = ror8_add(rr); \
  rr += __shfl_xor(rr, 16, 64); \
  rrc = rr; \
  if (seg == 0) part[(size_t)(rowchunk + (T_))*DD + h*HDIM + kq2*2 + klocal] = blg*rr; \
}

template<int ROT>
__device__ __forceinline__ void scan_body(int b, int h, int kq2, int l,
    const unsigned short* __restrict__ vals, const unsigned short* __restrict__ rkb,
    const float* __restrict__ scal, float* __restrict__ part,
    unsigned short (*s_rk)[64][64], unsigned short (*s_v)[64][8], float (*s_sc)[64][4])
{
  const int seg = l & 31, klocal = l >> 5;
  const int dbase = seg*2;
  const int vidx = (kq2 & 3)*2 + klocal;
  const int kq16 = kq2 >> 2;
  const int rowbase = b*TT;

  float S0 = 0.f, S1 = 0.f;
  float2 rb0 = make_float2(0.f,0.f), rb1 = rb0, rb2 = rb0, rb3 = rb0;
  float vb0 = 0.f, vb1 = 0.f;
  const float4 Z = make_float4(0.f,0.f,0.f,0.f);
  float4 sb0 = Z, sb1 = Z;
  float rrc = 0.f;    // carried read-dot == next step's pred

  auto stage = [&](int c, int pbuf){
    const int r0 = rowbase + c*64;
    #pragma unroll
    for (int i = 0; i < 8; ++i){
      const unsigned short* g = rkb + (size_t)(r0 + i*8 + (l>>3))*DD + h*HDIM + (l&7)*8;
      gl_lds16(g, &s_rk[pbuf][i*8][0]);
    }
    { const unsigned short* g = vals + ((size_t)(r0 + l)*MM + ROT)*DD + h*HDIM + kq16*8;
      gl_lds16(g, &s_v[pbuf][0][0]); }
    { const float* g = scal + ((size_t)(r0 + l)*MM + ROT)*(HH*4) + h*4;
      gl_lds16(g, &s_sc[pbuf][0][0]); }
  };

  stage(0, 0);
  for (int c = 0; c < TT/64; ++c){
    const int p = c & 1;
    __syncthreads();                 // vmcnt drain: chunk c staged
    if (c + 1 < TT/64) stage(c+1, p^1);
    { ushort2 r0v = *(const ushort2*)&s_rk[p][0][dbase];
      rb0.x = bf2f(r0v.x); rb0.y = bf2f(r0v.y);
      ushort2 r1v = *(const ushort2*)&s_rk[p][1][dbase];
      rb1.x = bf2f(r1v.x); rb1.y = bf2f(r1v.y); }
    vb0 = bf2f(s_v[p][0][vidx]); vb1 = bf2f(s_v[p][1][vidx]);
    sb0 = *(const float4*)&s_sc[p][0][0]; sb1 = *(const float4*)&s_sc[p][1][0];
    const int rowchunk = rowbase + c*64;
    for (int tt = 0; tt < 64; tt += 4){
      SSTEP(tt+0, rb3, rb0, rb2, vb0, sb0)
      SSTEP(tt+1, rb0, rb1, rb3, vb1, sb1)
      SSTEP(tt+2, rb1, rb2, rb0, vb0, sb0)
      SSTEP(tt+3, rb2, rb3, rb1, vb1, sb1)
    }
  }
}

__global__ void __launch_bounds__(64) k_scan(const unsigned short* __restrict__ vals,
                                             const unsigned short* __restrict__ rkb,
                                             const float* __restrict__ scal,
                                             float* __restrict__ partials){
  __shared__ unsigned short s_rk[2][64][64];   // bf16, 16KB
  __shared__ unsigned short s_v[2][64][8];     // 2KB
  __shared__ float s_sc[2][64][4];             // 2KB
  const int bi = blockIdx.x;      // (((b*HH)+h)*MM + m)*32 + kq2
  const int kq2 = bi & 31;
  const int m  = (bi >> 5) & 1;
  const int h  = (bi >> 6) & 3;
  const int b  = bi >> 8;
  float* part = partials + (size_t)m*(BB*TT*DD);
  if (m == 0) scan_body<0>(b, h, kq2, threadIdx.x, vals, rkb, scal, part, s_rk, s_v, s_sc);
  else        scan_body<1>(b, h, kq2, threadIdx.x, vals, rkb, scal, part, s_rk, s_v, s_sc);
}

extern "C" void kernel_launch(void* const* d_in, const int* in_sizes, int n_in,
                              void* d_out, int out_size, void* d_ws, size_t ws_size,
                              hipStream_t stream){
  const int*   ids   = (const int*)d_in[0];
  const float* emb   = (const float*)d_in[1];
  const float* normw = (const float*)d_in[2];
  const float* Wup   = (const float*)d_in[3];
  const float* Wgate = (const float*)d_in[4];
  const float* Wdown = (const float*)d_in[5];
  const float* convw = (const float*)d_in[6];
  const float* convb = (const float*)d_in[7];
  const float* Wv    = (const float*)d_in[8];
  const float* Wg    = (const float*)d_in[9];
  const float* Wb    = (const float*)d_in[10];
  const float* Wa    = (const float*)d_in[11];
  const float* A_log = (const float*)d_in[12];
  const float* dtb   = (const float*)d_in[13];
  const float* Wbl   = (const float*)d_in[14];
  const float* Wout  = (const float*)d_in[15];
  const float* fnw   = (const float*)d_in[16];
  float* out = (float*)d_out;

  const int ROWS = BB*TT;              // 4096
  const size_t MEG = 1u << 20;
  float* ws   = (float*)d_ws;
  float* x    = ws;                        // 1M f32 (residual)
  unsigned short* nyb = (unsigned short*)(x + MEG);    // 1M bf16 (nx / yb)
  float* big1 = x + MEG + MEG/2;           // 2M floats: ub | gb/hhb ; later valsb
  float* big2 = big1 + 2*MEG;              // 2M f32: partials
  float* y    = big2 + 2*MEG;              // 1M f32
  unsigned short* rkb = (unsigned short*)(y + MEG);    // 1M bf16
  float* scal = y + MEG + MEG/2;           // 128K f32
  unsigned short* wbf = (unsigned short*)(scal + (1u<<17));  // 1.25M ushorts

  unsigned short* ub  = (unsigned short*)big1;
  unsigned short* gb  = (unsigned short*)(big1 + MEG);
  unsigned short* valsb = ub;

  { int total = 2*LWB + VV*DD;
    k_cvt<<<(total + 255)/256, 256, 0, stream>>>(Wup, Wgate, Wdown, Wv, Wout, emb, wbf); }

  k_embed<<<ROWS, DD, 0, stream>>>(ids, emb, x);

  for (int l = 0; l < LL; ++l){
    unsigned short* wl = wbf + (size_t)l*LWB;
    unsigned short* upT   = wl;
    unsigned short* gateT = wl + 131072;
    unsigned short* downT = wl + 262144;
    unsigned short* wvT   = wl + 393216;
    unsigned short* woutT = wl + 524288;

    k_rmsnorm<<<ROWS, 64, 0, stream>>>(x, normw + l*DD, nyb);
    k_gemm_up<<<dim3(DIM/64, ROWS/128), 256, 0, stream>>>(nyb, upT, gateT, ub, gb);
    k_conv<<<(ROWS*DIM/8)/256, 256, 0, stream>>>(ub, gb, convw + l*DIM*KW, convb + l*DIM, gb);
    k_gemm64<2><<<dim3(DD/64, ROWS/64), 256, 0, stream>>>(gb, downT, y, nyb, DD, DIM);
    k_gemm128<1><<<dim3(DIM/64, ROWS/128), 256, 0, stream>>>(nyb, wvT, nullptr, valsb, DIM, DD);
    k_fused<<<ROWS/4, 256, 0, stream>>>(y, Wg + l*DD*HH, Wb + (size_t)l*MM*DD*HH,
                                        Wa + (size_t)l*MM*DD*HH, Wbl + l*DD*HH*MM,
                                        A_log + l*MM*HH, dtb + l*MM*HH, rkb, scal);
    k_scan<<<BB*HH*MM*32, 64, 0, stream>>>(valsb, rkb, scal, big2);
    k_gemm_wout<<<dim3(DD/64, ROWS/64), 256, 0, stream>>>(big2, big2 + MEG, woutT, y, x);
  }

  unsigned short* embT = wbf + 2*LWB;   // [272][256] bf16
  k_rmsnorm<<<ROWS, 64, 0, stream>>>(x, fnw, nyb);
  k_gemm64<0><<<dim3((VV+63)/64, ROWS/64), 256, 0, stream>>>(nyb, embT, out, nullptr, VV, DD);
}

// Round 16
// 287.531 us; speedup vs baseline: 1.0836x; 1.0836x over previous
//
#include <hip/hip_runtime.h>
#include <math.h>

#define BB 8
#define TT 512
#define DD 256
#define DIM 512
#define KW 4
#define MM 2
#define HH 4
#define HDIM 64
#define LL 2
#define VV 272

typedef __attribute__((ext_vector_type(8))) short bf16x8;
typedef __attribute__((ext_vector_type(4))) float f32x4;

__device__ __forceinline__ float sigf(float x){ return 1.f/(1.f+__expf(-x)); }
__device__ __forceinline__ float siluf(float x){ return x/(1.f+__expf(-x)); }

__device__ __forceinline__ unsigned short f2bf(float f){
  unsigned int u = __float_as_uint(f);
  unsigned int r = (u + 0x7FFFu + ((u >> 16) & 1u)) >> 16;
  return (unsigned short)r;
}
__device__ __forceinline__ float bf2f(unsigned short s){
  return __uint_as_float(((unsigned int)s) << 16);
}

// DPP reduces (no DS ops)
__device__ __forceinline__ float xor1_add(float x){
  int y = __builtin_amdgcn_update_dpp(0, __float_as_int(x), 0xB1, 0xF, 0xF, true);
  return x + __int_as_float(y);
}
__device__ __forceinline__ float xor2_add(float x){
  int y = __builtin_amdgcn_update_dpp(0, __float_as_int(x), 0x4E, 0xF, 0xF, true);
  return x + __int_as_float(y);
}
__device__ __forceinline__ float ror4_add(float x){
  int y = __builtin_amdgcn_update_dpp(0, __float_as_int(x), 0x124, 0xF, 0xF, true);
  return x + __int_as_float(y);
}
__device__ __forceinline__ float ror8_add(float x){
  int y = __builtin_amdgcn_update_dpp(0, __float_as_int(x), 0x128, 0xF, 0xF, true);
  return x + __int_as_float(y);
}

// async global->LDS, 16B per lane. LDS dest is wave-uniform base + lane*16.
__device__ __forceinline__ void gl_lds16(const void* g, void* l){
  __builtin_amdgcn_global_load_lds(
      (const __attribute__((address_space(1))) unsigned int*)g,
      (__attribute__((address_space(3))) unsigned int*)l,
      16, 0, 0);
}

// ---------------- weight convert + transpose to bf16 [N][K] ----------------
#define LWB 589824
__global__ void k_cvt(const float* __restrict__ Wup, const float* __restrict__ Wgate,
                      const float* __restrict__ Wdown, const float* __restrict__ Wv,
                      const float* __restrict__ Wout, const float* __restrict__ emb,
                      unsigned short* __restrict__ wbf){
  int idx = blockIdx.x*256 + threadIdx.x;
  if (idx >= 2*LWB + VV*DD) return;
  float v;
  if (idx < 2*LWB){
    int l = (idx >= LWB) ? 1 : 0;
    int local = idx - l*LWB;
    if (local < 131072){ int n = local>>8, k = local&255;
      v = Wup[(size_t)l*131072 + k*DIM + n]; }
    else if (local < 262144){ local -= 131072; int n = local>>8, k = local&255;
      v = Wgate[(size_t)l*131072 + k*DIM + n]; }
    else if (local < 393216){ local -= 262144; int n = local>>9, k = local&511;
      v = Wdown[(size_t)l*131072 + k*DD + n]; }
    else if (local < 524288){ local -= 393216; int n = local>>8, k = local&255;
      v = Wv[(size_t)l*131072 + k*DIM + n]; }
    else { local -= 524288; int n = local>>8, k = local&255;
      v = Wout[(size_t)l*65536 + k*DD + n]; }
  } else {
    v = emb[idx - 2*LWB];
  }
  wbf[idx] = f2bf(v);
}

// ------- fused embedding gather + rmsnorm (layer 0): x and nx in one pass ---
__global__ void __launch_bounds__(256) k_embed_norm(const int* __restrict__ ids,
                                                    const float* __restrict__ emb,
                                                    const float* __restrict__ w,
                                                    float* __restrict__ x,
                                                    unsigned short* __restrict__ out){
  const int wv = threadIdx.x >> 6, l = threadIdx.x & 63;
  const int row = blockIdx.x*4 + wv;
  float4 v = *(const float4*)&emb[(size_t)ids[row]*DD + l*4];
  *(float4*)&x[(size_t)row*DD + l*4] = v;
  float ss = v.x*v.x + v.y*v.y + v.z*v.z + v.w*v.w;
  #pragma unroll
  for (int o = 32; o > 0; o >>= 1) ss += __shfl_xor(ss, o, 64);
  float sc = rsqrtf(ss*(1.f/DD) + 1e-6f);
  float4 wvv = *(const float4*)&w[l*4];
  ushort4 r;
  r.x = f2bf(v.x*sc*wvv.x); r.y = f2bf(v.y*sc*wvv.y);
  r.z = f2bf(v.z*sc*wvv.z); r.w = f2bf(v.w*sc*wvv.w);
  *(ushort4*)&out[(size_t)row*DD + l*4] = r;
}

// ---------------- rmsnorm -> bf16 out, 4 rows/block (4 waves) ----------------
__global__ void __launch_bounds__(256) k_rmsnorm(const float* __restrict__ in,
                                                 const float* __restrict__ w,
                                                 unsigned short* __restrict__ out){
  const int wv = threadIdx.x >> 6, l = threadIdx.x & 63;
  const int row = blockIdx.x*4 + wv;
  float4 v = *(const float4*)&in[(size_t)row*DD + l*4];
  float ss = v.x*v.x + v.y*v.y + v.z*v.z + v.w*v.w;
  #pragma unroll
  for (int o = 32; o > 0; o >>= 1) ss += __shfl_xor(ss, o, 64);
  float sc = rsqrtf(ss*(1.f/DD) + 1e-6f);
  float4 wvv = *(const float4*)&w[l*4];
  ushort4 r;
  r.x = f2bf(v.x*sc*wvv.x); r.y = f2bf(v.y*sc*wvv.y);
  r.z = f2bf(v.z*sc*wvv.z); r.w = f2bf(v.w*sc*wvv.w);
  *(ushort4*)&out[(size_t)row*DD + l*4] = r;
}

// -------- bf16 GEMM 64x64 tile (4 waves): C[4096,N] = A@Bt^T ----------------
// MODE 0: f32 C. MODE 1: bf16 C. MODE 2: both.
template<int MODE>
__global__ void __launch_bounds__(256) k_gemm64(const unsigned short* __restrict__ A,
                                                const unsigned short* __restrict__ Bt,
                                                float* __restrict__ Cf,
                                                unsigned short* __restrict__ Cb,
                                                int N, int K){
  __shared__ unsigned short as[64][72];
  __shared__ unsigned short bs[64][72];
  const int tid = threadIdx.x;
  const int w = tid >> 6, l = tid & 63;
  const int m0 = blockIdx.y*64, n0 = blockIdx.x*64;
  const int ar = tid >> 2, ac = (tid & 3)*16;
  f32x4 acc[4] = {};
  for (int k0 = 0; k0 < K; k0 += 64){
    { const bf16x8* src = (const bf16x8*)&A[(size_t)(m0+ar)*K + k0 + ac];
      *(bf16x8*)&as[ar][ac]   = src[0];
      *(bf16x8*)&as[ar][ac+8] = src[1];
    }
    { int n = n0 + ar;
      bf16x8 z; z = (bf16x8)(short)0;
      bf16x8 b0 = z, b1 = z;
      if (n < N){
        const bf16x8* src = (const bf16x8*)&Bt[(size_t)n*K + k0 + ac];
        b0 = src[0]; b1 = src[1];
      }
      *(bf16x8*)&bs[ar][ac]   = b0;
      *(bf16x8*)&bs[ar][ac+8] = b1;
    }
    __syncthreads();
    const int mr = w*16 + (l & 15);
    const int kb = (l >> 4)*8;
    #pragma unroll
    for (int kc2 = 0; kc2 < 2; ++kc2){
      bf16x8 af = *(const bf16x8*)&as[mr][kc2*32 + kb];
      #pragma unroll
      for (int nt = 0; nt < 4; ++nt){
        bf16x8 bfr = *(const bf16x8*)&bs[nt*16 + (l & 15)][kc2*32 + kb];
        acc[nt] = __builtin_amdgcn_mfma_f32_16x16x32_bf16(af, bfr, acc[nt], 0, 0, 0);
      }
    }
    __syncthreads();
  }
  #pragma unroll
  for (int nt = 0; nt < 4; ++nt){
    int col = n0 + nt*16 + (l & 15);
    if (col < N){
      #pragma unroll
      for (int r = 0; r < 4; ++r){
        int row = m0 + w*16 + (l >> 4)*4 + r;
        if (MODE == 0 || MODE == 2) Cf[(size_t)row*N + col] = acc[nt][r];
        if (MODE == 1 || MODE == 2) Cb[(size_t)row*N + col] = f2bf(acc[nt][r]);
      }
    }
  }
}

// -------- bf16 GEMM 128x64 tile (4 waves) — for full-grid cases ------------
template<int MODE>
__global__ void __launch_bounds__(256) k_gemm128(const unsigned short* __restrict__ A,
                                                 const unsigned short* __restrict__ Bt,
                                                 float* __restrict__ Cf,
                                                 unsigned short* __restrict__ Cb,
                                                 int N, int K){
  __shared__ unsigned short as[128][72];
  __shared__ unsigned short bs[64][72];
  const int tid = threadIdx.x;
  const int w = tid >> 6, l = tid & 63;
  const int m0 = blockIdx.y*128, n0 = blockIdx.x*64;
  const int ar = tid >> 1, ac = (tid & 1)*32;
  const int br = tid >> 2, bc = (tid & 3)*16;
  f32x4 acc[2][4] = {};
  for (int k0 = 0; k0 < K; k0 += 64){
    { const bf16x8* src = (const bf16x8*)&A[(size_t)(m0+ar)*K + k0 + ac];
      *(bf16x8*)&as[ar][ac]    = src[0];
      *(bf16x8*)&as[ar][ac+8]  = src[1];
      *(bf16x8*)&as[ar][ac+16] = src[2];
      *(bf16x8*)&as[ar][ac+24] = src[3];
    }
    { int n = n0 + br;
      bf16x8 z; z = (bf16x8)(short)0;
      bf16x8 b0 = z, b1 = z;
      if (n < N){
        const bf16x8* s = (const bf16x8*)&Bt[(size_t)n*K + k0 + bc];
        b0 = s[0]; b1 = s[1];
      }
      *(bf16x8*)&bs[br][bc]   = b0;
      *(bf16x8*)&bs[br][bc+8] = b1;
    }
    __syncthreads();
    const int lr = l & 15, kb = (l >> 4)*8;
    #pragma unroll
    for (int kc2 = 0; kc2 < 2; ++kc2){
      bf16x8 af0 = *(const bf16x8*)&as[w*32 + lr][kc2*32 + kb];
      bf16x8 af1 = *(const bf16x8*)&as[w*32 + 16 + lr][kc2*32 + kb];
      #pragma unroll
      for (int nt = 0; nt < 4; ++nt){
        bf16x8 bfr = *(const bf16x8*)&bs[nt*16 + lr][kc2*32 + kb];
        acc[0][nt] = __builtin_amdgcn_mfma_f32_16x16x32_bf16(af0, bfr, acc[0][nt], 0, 0, 0);
        acc[1][nt] = __builtin_amdgcn_mfma_f32_16x16x32_bf16(af1, bfr, acc[1][nt], 0, 0, 0);
      }
    }
    __syncthreads();
  }
  const int lr = l & 15;
  #pragma unroll
  for (int mt = 0; mt < 2; ++mt){
    #pragma unroll
    for (int nt = 0; nt < 4; ++nt){
      int col = n0 + nt*16 + lr;
      if (col < N){
        #pragma unroll
        for (int r = 0; r < 4; ++r){
          int row = m0 + w*32 + mt*16 + (l >> 4)*4 + r;
          if (MODE == 0 || MODE == 2) Cf[(size_t)row*N + col] = acc[mt][nt][r];
          if (MODE == 1 || MODE == 2) Cb[(size_t)row*N + col] = f2bf(acc[mt][nt][r]);
        }
      }
    }
  }
}

// ---- dual GEMM: Cu = A@BuT^T, Cg = A@BgT^T (shared A), BM=128 BN=64 -------
__global__ void __launch_bounds__(256) k_gemm_up(const unsigned short* __restrict__ A,
                                                 const unsigned short* __restrict__ But,
                                                 const unsigned short* __restrict__ Bgt,
                                                 unsigned short* __restrict__ Cu,
                                                 unsigned short* __restrict__ Cg){
  __shared__ unsigned short as[128][72];
  __shared__ unsigned short bu[64][72];
  __shared__ unsigned short bg[64][72];
  const int tid = threadIdx.x;
  const int w = tid >> 6, l = tid & 63;
  const int m0 = blockIdx.y*128, n0 = blockIdx.x*64;
  const int ar = tid >> 1, ac = (tid & 1)*32;
  const int br = tid >> 2, bc = (tid & 3)*16;
  f32x4 accu[2][4] = {}; f32x4 accg[2][4] = {};
  for (int k0 = 0; k0 < DD; k0 += 64){
    { const bf16x8* src = (const bf16x8*)&A[(size_t)(m0+ar)*DD + k0 + ac];
      *(bf16x8*)&as[ar][ac]    = src[0];
      *(bf16x8*)&as[ar][ac+8]  = src[1];
      *(bf16x8*)&as[ar][ac+16] = src[2];
      *(bf16x8*)&as[ar][ac+24] = src[3];
    }
    { const bf16x8* s0 = (const bf16x8*)&But[(size_t)(n0+br)*DD + k0 + bc];
      *(bf16x8*)&bu[br][bc]   = s0[0];
      *(bf16x8*)&bu[br][bc+8] = s0[1];
      const bf16x8* s1 = (const bf16x8*)&Bgt[(size_t)(n0+br)*DD + k0 + bc];
      *(bf16x8*)&bg[br][bc]   = s1[0];
      *(bf16x8*)&bg[br][bc+8] = s1[1];
    }
    __syncthreads();
    const int lr = l & 15, kb = (l >> 4)*8;
    #pragma unroll
    for (int kc2 = 0; kc2 < 2; ++kc2){
      bf16x8 af0 = *(const bf16x8*)&as[w*32 + lr][kc2*32 + kb];
      bf16x8 af1 = *(const bf16x8*)&as[w*32 + 16 + lr][kc2*32 + kb];
      #pragma unroll
      for (int nt = 0; nt < 4; ++nt){
        bf16x8 b0 = *(const bf16x8*)&bu[nt*16 + lr][kc2*32 + kb];
        accu[0][nt] = __builtin_amdgcn_mfma_f32_16x16x32_bf16(af0, b0, accu[0][nt], 0, 0, 0);
        accu[1][nt] = __builtin_amdgcn_mfma_f32_16x16x32_bf16(af1, b0, accu[1][nt], 0, 0, 0);
        bf16x8 b1 = *(const bf16x8*)&bg[nt*16 + lr][kc2*32 + kb];
        accg[0][nt] = __builtin_amdgcn_mfma_f32_16x16x32_bf16(af0, b1, accg[0][nt], 0, 0, 0);
        accg[1][nt] = __builtin_amdgcn_mfma_f32_16x16x32_bf16(af1, b1, accg[1][nt], 0, 0, 0);
      }
    }
    __syncthreads();
  }
  const int lr = l & 15;
  #pragma unroll
  for (int mt = 0; mt < 2; ++mt){
    #pragma unroll
    for (int nt = 0; nt < 4; ++nt){
      int col = n0 + nt*16 + lr;
      #pragma unroll
      for (int r = 0; r < 4; ++r){
        int row = m0 + w*32 + mt*16 + (l >> 4)*4 + r;
        Cu[(size_t)row*DIM + col] = f2bf(accu[mt][nt][r]);
        Cg[(size_t)row*DIM + col] = f2bf(accg[mt][nt][r]);
      }
    }
  }
}

// ---- Wout GEMM 64x64: fused comb (A = p0+p1) + resid (x += y + A@WoutT^T) --
__global__ void __launch_bounds__(256) k_gemm_wout(const float* __restrict__ p0,
                                                   const float* __restrict__ p1,
                                                   const unsigned short* __restrict__ Bt,
                                                   const float* __restrict__ y,
                                                   float* __restrict__ x){
  __shared__ unsigned short as[64][72];
  __shared__ unsigned short bs[64][72];
  const int tid = threadIdx.x;
  const int w = tid >> 6, l = tid & 63;
  const int m0 = blockIdx.y*64, n0 = blockIdx.x*64;
  const int ar = tid >> 2, ac = (tid & 3)*16;
  f32x4 acc[4] = {};
  for (int k0 = 0; k0 < DD; k0 += 64){
    #pragma unroll
    for (int j = 0; j < 4; ++j){
      size_t off = (size_t)(m0+ar)*DD + k0 + ac + j*4;
      float4 a = *(const float4*)&p0[off];
      float4 b = *(const float4*)&p1[off];
      a.x += b.x; a.y += b.y; a.z += b.z; a.w += b.w;
      ushort4 u = make_ushort4(f2bf(a.x), f2bf(a.y), f2bf(a.z), f2bf(a.w));
      *(ushort4*)&as[ar][ac + j*4] = u;
    }
    { const bf16x8* src = (const bf16x8*)&Bt[(size_t)(n0+ar)*DD + k0 + ac];
      *(bf16x8*)&bs[ar][ac]   = src[0];
      *(bf16x8*)&bs[ar][ac+8] = src[1];
    }
    __syncthreads();
    const int mr = w*16 + (l & 15);
    const int kb = (l >> 4)*8;
    #pragma unroll
    for (int kc2 = 0; kc2 < 2; ++kc2){
      bf16x8 af = *(const bf16x8*)&as[mr][kc2*32 + kb];
      #pragma unroll
      for (int nt = 0; nt < 4; ++nt){
        bf16x8 bfr = *(const bf16x8*)&bs[nt*16 + (l & 15)][kc2*32 + kb];
        acc[nt] = __builtin_amdgcn_mfma_f32_16x16x32_bf16(af, bfr, acc[nt], 0, 0, 0);
      }
    }
    __syncthreads();
  }
  #pragma unroll
  for (int nt = 0; nt < 4; ++nt){
    int col = n0 + nt*16 + (l & 15);
    #pragma unroll
    for (int r = 0; r < 4; ++r){
      int row = m0 + w*16 + (l >> 4)*4 + r;
      size_t off = (size_t)row*DD + col;
      x[off] = x[off] + y[off] + acc[nt][r];
    }
  }
}

// ------------ causal depthwise conv + silu gating, bf16 in/out ------------
__global__ void k_conv(const unsigned short* __restrict__ u,
                       const unsigned short* __restrict__ g,
                       const float* __restrict__ cw, const float* __restrict__ cb,
                       unsigned short* __restrict__ hh){
  int i8 = blockIdx.x*256 + threadIdx.x;    // over ROWS*DIM/8
  int cg = i8 & 63;
  int bt = i8 >> 6;
  int t  = bt & (TT-1);
  int c0 = cg*8;
  float acc[8];
  { float4 b0 = *(const float4*)&cb[c0];
    float4 b1 = *(const float4*)&cb[c0+4];
    acc[0]=b0.x; acc[1]=b0.y; acc[2]=b0.z; acc[3]=b0.w;
    acc[4]=b1.x; acc[5]=b1.y; acc[6]=b1.z; acc[7]=b1.w; }
  float wts[8][4];
  #pragma unroll
  for (int i = 0; i < 8; ++i) *(float4*)&wts[i][0] = *(const float4*)&cw[(c0+i)*KW];
  #pragma unroll
  for (int j = 0; j < KW; ++j){
    int dt_ = j - (KW-1);
    if (t + dt_ >= 0){
      bf16x8 uv = *(const bf16x8*)&u[(size_t)(bt + dt_)*DIM + c0];
      #pragma unroll
      for (int i = 0; i < 8; ++i)
        acc[i] = fmaf(bf2f((unsigned short)uv[i]), wts[i][j], acc[i]);
    }
  }
  bf16x8 gv = *(const bf16x8*)&g[(size_t)bt*DIM + c0];
  bf16x8 o;
  #pragma unroll
  for (int i = 0; i < 8; ++i){
    float h = siluf(acc[i]);
    o[i] = (short)f2bf(siluf(bf2f((unsigned short)gv[i])) * h);
  }
  *(bf16x8*)&hh[(size_t)bt*DIM + c0] = o;
}

// ---- fused: proj(small GEMM w/ packed weights) + scal + rk-normalize ----
__global__ void __launch_bounds__(256) k_fused(const float* __restrict__ y,
    const float* __restrict__ Wg, const float* __restrict__ Wb,
    const float* __restrict__ Wa, const float* __restrict__ Wbl,
    const float* __restrict__ A_log, const float* __restrict__ dtb,
    float* __restrict__ rkb, float* __restrict__ scal){
  __shared__ float s_y[4][260];
  __shared__ float s_p[4][32];
  const int wv = threadIdx.x >> 6, l = threadIdx.x & 63;
  const int row = blockIdx.x*4 + wv;

  float4 yv = *(const float4*)&y[(size_t)row*DD + l*4];
  *(float4*)&s_y[wv][l*4] = yv;

  float ss = yv.x*yv.x + yv.y*yv.y + yv.z*yv.z + yv.w*yv.w;
  ss = xor1_add(ss); ss = xor2_add(ss);
  ss = ror4_add(ss); ss = ror8_add(ss);
  float inv = 1.f / fmaxf(sqrtf(ss), 1e-12f);
  float4 rv; rv.x = yv.x*inv; rv.y = yv.y*inv; rv.z = yv.z*inv; rv.w = yv.w*inv;
  *(float4*)&rkb[(size_t)row*DD + l*4] = rv;

  __syncthreads();

  const int j = (l < 28) ? l : 27;
  const float* wp; int stride;
  if (j < 4){ wp = Wg + j; stride = HH; }
  else if (j < 12){ int m=(j-4)>>2, h=(j-4)&3; wp = Wb + (size_t)m*DD*HH + h; stride = HH; }
  else if (j < 20){ int m=(j-12)>>2, h=(j-12)&3; wp = Wa + (size_t)m*DD*HH + h; stride = HH; }
  else { wp = Wbl + (j-20); stride = HH*MM; }
  float a0=0.f,a1=0.f,a2=0.f,a3=0.f;
  #pragma unroll 4
  for (int k = 0; k < DD; k += 4){
    a0 = fmaf(s_y[wv][k+0], wp[(k+0)*stride], a0);
    a1 = fmaf(s_y[wv][k+1], wp[(k+1)*stride], a1);
    a2 = fmaf(s_y[wv][k+2], wp[(k+2)*stride], a2);
    a3 = fmaf(s_y[wv][k+3], wp[(k+3)*stride], a3);
  }
  if (l < 28) s_p[wv][l] = (a0+a1)+(a2+a3);

  __syncthreads();

  if (l < 8){
    int m = l >> 2, h = l & 3;
    float gs  = sigf(s_p[wv][h]);
    float btv = sigf(s_p[wv][4 + m*4 + h]);
    float sp  = s_p[wv][12 + m*4 + h] + dtb[m*HH + h];
    sp = (sp > 15.f) ? sp : log1pf(__expf(sp));
    float dc  = __expf(-__expf(A_log[m*HH + h]) * sp);
    float l0 = s_p[wv][20 + h*2], l1 = s_p[wv][20 + h*2 + 1];
    float mx = fmaxf(l0, l1);
    float e0 = __expf(l0-mx), e1 = __expf(l1-mx);
    float bl = (m ? e1 : e0) / (e0 + e1);
    float4 o; o.x = dc; o.y = btv; o.z = bl*gs; o.w = 0.f;
    *(float4*)&scal[((size_t)row*MM + m)*(HH*4) + h*4] = o;
  }
}

// ---------------- sequential delta-memory scan, d-split-16 (R13) ----------
// grid = B*H*M*16 blocks (k-split by 16), 64 threads = 1 wave.
// Lane: seg = l&15 (d in [seg*4, seg*4+4), S[4]/lane); klocal = l>>4 (4 k).
// d-reduce over the 16-lane row: xor1 + xor2 + ror4 + ror8 (all DPP).
// pred(t+1) = read(t) carried in rrc. v staged bf16 at kq8 = kq4>>1 granularity.

#define SSTEP(T_, WK, RK, PF, VB, SB) { \
  const float dc = SB.x, btv = SB.y, blg = SB.z; \
  const float v = VB; \
  { const int tn_ = ((T_)+2 < 64) ? (T_)+2 : 63; \
    PF = *(const float4*)&s_rk[p][tn_][dbase]; \
    VB = bf2f(s_v[p][tn_][vidx]); \
    SB = *(const float4*)&s_sc[p][tn_][0]; } \
  const float err = (v - dc*rrc)*btv; \
  float rr0=0.f, rr1=0.f; \
  { const float4 rp = WK; const float4 rc = RK; \
    float w0,w1,w2,w3,c0,c1,c2,c3; \
    if (ROT == 0){ w0=rp.x; w1=rp.y; w2=rp.z; w3=rp.w; c0=rc.x; c1=rc.y; c2=rc.z; c3=rc.w; } \
    else { w0=-rp.y; w1=rp.x; w2=-rp.w; w3=rp.z; c0=-rc.y; c1=rc.x; c2=-rc.w; c3=rc.z; } \
    S[0] = fmaf(S[0], dc, w0*err); rr0 = fmaf(S[0], c0, rr0); \
    S[1] = fmaf(S[1], dc, w1*err); rr1 = fmaf(S[1], c1, rr1); \
    S[2] = fmaf(S[2], dc, w2*err); rr0 = fmaf(S[2], c2, rr0); \
    S[3] = fmaf(S[3], dc, w3*err); rr1 = fmaf(S[3], c3, rr1); } \
  float rr = rr0 + rr1; \
  rr = xor1_add(rr); rr = xor2_add(rr); rr = ror4_add(rr); rr = ror8_add(rr); \
  rrc = rr; \
  if (seg == 0) part[(size_t)(rowchunk + (T_))*DD + h*HDIM + kq4*4 + klocal] = blg*rr; \
}

template<int ROT>
__device__ __forceinline__ void scan_body(int b, int h, int kq4, int l,
    const unsigned short* __restrict__ vals, const float* __restrict__ rkb,
    const float* __restrict__ scal, float* __restrict__ part,
    float (*s_rk)[64][64], unsigned short (*s_v)[64][8], float (*s_sc)[64][4])
{
  const int seg = l & 15, klocal = l >> 4;
  const int dbase = seg*4;
  const int vidx = (kq4 & 1)*4 + klocal;
  const int kq8 = kq4 >> 1;
  const int rowbase = b*TT;

  float S[4];
  #pragma unroll
  for (int j = 0; j < 4; ++j) S[j] = 0.f;
  const float4 Z = make_float4(0.f,0.f,0.f,0.f);
  float4 rb0 = Z, rb1 = Z, rb2 = Z, rb3 = Z;
  float vb0 = 0.f, vb1 = 0.f;
  float4 sb0 = Z, sb1 = Z;
  float rrc = 0.f;    // carried read-dot == next step's pred

  auto stage = [&](int c, int pbuf){
    const int r0 = rowbase + c*64;
    #pragma unroll
    for (int i = 0; i < 16; ++i){
      const float* g = rkb + (size_t)(r0 + i*4 + (l>>4))*DD + h*HDIM + (l&15)*4;
      gl_lds16(g, &s_rk[pbuf][i*4][0]);
    }
    { const unsigned short* g = vals + ((size_t)(r0 + l)*MM + ROT)*DD + h*HDIM + kq8*8;
      gl_lds16(g, &s_v[pbuf][0][0]); }
    { const float* g = scal + ((size_t)(r0 + l)*MM + ROT)*(HH*4) + h*4;
      gl_lds16(g, &s_sc[pbuf][0][0]); }
  };

  stage(0, 0);
  for (int c = 0; c < TT/64; ++c){
    const int p = c & 1;
    __syncthreads();                 // vmcnt drain: chunk c staged
    if (c + 1 < TT/64) stage(c+1, p^1);
    rb0 = *(const float4*)&s_rk[p][0][dbase];
    rb1 = *(const float4*)&s_rk[p][1][dbase];
    vb0 = bf2f(s_v[p][0][vidx]); vb1 = bf2f(s_v[p][1][vidx]);
    sb0 = *(const float4*)&s_sc[p][0][0]; sb1 = *(const float4*)&s_sc[p][1][0];
    const int rowchunk = rowbase + c*64;
    for (int tt = 0; tt < 64; tt += 4){
      SSTEP(tt+0, rb3, rb0, rb2, vb0, sb0)
      SSTEP(tt+1, rb0, rb1, rb3, vb1, sb1)
      SSTEP(tt+2, rb1, rb2, rb0, vb0, sb0)
      SSTEP(tt+3, rb2, rb3, rb1, vb1, sb1)
    }
  }
}

__global__ void __launch_bounds__(64) k_scan(const unsigned short* __restrict__ vals,
                                             const float* __restrict__ rkb,
                                             const float* __restrict__ scal,
                                             float* __restrict__ partials){
  __shared__ float s_rk[2][64][64];
  __shared__ unsigned short s_v[2][64][8];
  __shared__ float s_sc[2][64][4];
  const int bi = blockIdx.x;      // (((b*HH)+h)*MM + m)*16 + kq4
  const int kq4 = bi & 15;
  const int m  = (bi >> 4) & 1;
  const int h  = (bi >> 5) & 3;
  const int b  = bi >> 7;
  float* part = partials + (size_t)m*(BB*TT*DD);
  if (m == 0) scan_body<0>(b, h, kq4, threadIdx.x, vals, rkb, scal, part, s_rk, s_v, s_sc);
  else        scan_body<1>(b, h, kq4, threadIdx.x, vals, rkb, scal, part, s_rk, s_v, s_sc);
}

extern "C" void kernel_launch(void* const* d_in, const int* in_sizes, int n_in,
                              void* d_out, int out_size, void* d_ws, size_t ws_size,
                              hipStream_t stream){
  const int*   ids   = (const int*)d_in[0];
  const float* emb   = (const float*)d_in[1];
  const float* normw = (const float*)d_in[2];
  const float* Wup   = (const float*)d_in[3];
  const float* Wgate = (const float*)d_in[4];
  const float* Wdown = (const float*)d_in[5];
  const float* convw = (const float*)d_in[6];
  const float* convb = (const float*)d_in[7];
  const float* Wv    = (const float*)d_in[8];
  const float* Wg    = (const float*)d_in[9];
  const float* Wb    = (const float*)d_in[10];
  const float* Wa    = (const float*)d_in[11];
  const float* A_log = (const float*)d_in[12];
  const float* dtb   = (const float*)d_in[13];
  const float* Wbl   = (const float*)d_in[14];
  const float* Wout  = (const float*)d_in[15];
  const float* fnw   = (const float*)d_in[16];
  float* out = (float*)d_out;

  const int ROWS = BB*TT;              // 4096
  const size_t MEG = 1u << 20;
  float* ws   = (float*)d_ws;
  float* x    = ws;                        // 1M f32 (residual)
  unsigned short* nyb = (unsigned short*)(x + MEG);    // 1M bf16 (nx / yb)
  float* big1 = x + MEG + MEG/2;           // 2M floats: ub | gb/hhb ; later valsb
  float* big2 = big1 + 2*MEG;              // 2M f32: partials
  float* y    = big2 + 2*MEG;              // 1M f32
  float* rkb  = y    + MEG;                // 1M f32
  float* scal = rkb  + MEG;                // 128K f32
  unsigned short* wbf = (unsigned short*)(scal + (1u<<17));  // 1.25M ushorts

  unsigned short* ub  = (unsigned short*)big1;
  unsigned short* gb  = (unsigned short*)(big1 + MEG);
  unsigned short* valsb = ub;

  { int total = 2*LWB + VV*DD;
    k_cvt<<<(total + 255)/256, 256, 0, stream>>>(Wup, Wgate, Wdown, Wv, Wout, emb, wbf); }

  // fused embed + layer-0 rmsnorm
  k_embed_norm<<<ROWS/4, 256, 0, stream>>>(ids, emb, normw, x, nyb);

  for (int l = 0; l < LL; ++l){
    unsigned short* wl = wbf + (size_t)l*LWB;
    unsigned short* upT   = wl;
    unsigned short* gateT = wl + 131072;
    unsigned short* downT = wl + 262144;
    unsigned short* wvT   = wl + 393216;
    unsigned short* woutT = wl + 524288;

    if (l > 0) k_rmsnorm<<<ROWS/4, 256, 0, stream>>>(x, normw + l*DD, nyb);
    k_gemm_up<<<dim3(DIM/64, ROWS/128), 256, 0, stream>>>(nyb, upT, gateT, ub, gb);
    k_conv<<<(ROWS*DIM/8)/256, 256, 0, stream>>>(ub, gb, convw + l*DIM*KW, convb + l*DIM, gb);
    k_gemm64<2><<<dim3(DD/64, ROWS/64), 256, 0, stream>>>(gb, downT, y, nyb, DD, DIM);
    k_gemm128<1><<<dim3(DIM/64, ROWS/128), 256, 0, stream>>>(nyb, wvT, nullptr, valsb, DIM, DD);
    k_fused<<<ROWS/4, 256, 0, stream>>>(y, Wg + l*DD*HH, Wb + (size_t)l*MM*DD*HH,
                                        Wa + (size_t)l*MM*DD*HH, Wbl + l*DD*HH*MM,
                                        A_log + l*MM*HH, dtb + l*MM*HH, rkb, scal);
    k_scan<<<BB*HH*MM*16, 64, 0, stream>>>(valsb, rkb, scal, big2);
    k_gemm_wout<<<dim3(DD/64, ROWS/64), 256, 0, stream>>>(big2, big2 + MEG, woutT, y, x);
  }

  unsigned short* embT = wbf + 2*LWB;   // [272][256] bf16
  k_rmsnorm<<<ROWS/4, 256, 0, stream>>>(x, fnw, nyb);
  k_gemm64<0><<<dim3((VV+63)/64, ROWS/64), 256, 0, stream>>>(nyb, embT, out, nullptr, VV, DD);
}